// Round 5
// baseline (275.410 us; speedup 1.0000x reference)
//
#include <hip/hip_runtime.h>
#include <math.h>

// Problem constants (x: [4, 64, 384, 384] fp32)
#define QLS_T   256            // B*C = 4*64, sequential scan axis
#define QLS_HW  (384 * 384)    // independent spatial locations
#define NSPLIT  4              // scan-axis split factor (partials via log-add-exp)
#define TPER    (QLS_T / NSPLIT)  // 64 planes per slice
#define PF      8              // prefetch depth within a slice

// Quantizer constants from the reference
#define Q_SCALE      16.0f
#define INV_Q_SCALE  (1.0f / 16.0f)
#define QMAXF        7.9375f
#define QMINF        (-8.0f)
#define LUT_IN_SCALE 4096.0f
#define LUT_IN_MAX   32767.0f
#define INV_LUT_OUT  (1.0f / 65536.0f)

// log1p(exp(-d)) = log2(1 + 2^(-d*log2e)) * ln2 on raw v_exp_f32/v_log_f32.
#define NEG_LOG2E_DIV (-1.4426950408889634f / 4096.0f)
#define LN2_X_65536   45426.09375f

// Native vector type: __builtin_nontemporal_store rejects HIP_vector_type
// (R4 compile failure); ext_vector_type floats are accepted and still emit
// global_load_dwordx4 / global_store_dwordx4 nt.
typedef float v4f __attribute__((ext_vector_type(4)));

// R3 post-mortem: per-wave prefetch depth (8->16) changed nothing; the
// 105us plateau is chip-level latency/occupancy (9 waves/CU, bursty
// load-then-wait). This round: 4-way T-split -> 36 waves/CU. The combine
// op is symmetric log-add-exp on the quantized grid, so 64-plane partials
// (each with its own -8 init) merge with the same operator; the 3 phantom
// exp(-8) terms shift s by ~5e-5 << half an output grid step.
__device__ __forceinline__ float qls_combine(float s, float v) {
    float diff  = fabsf(s - v);
    float d_int = fminf(floorf(diff * LUT_IN_SCALE), LUT_IN_MAX);
    float e     = __builtin_amdgcn_exp2f(d_int * NEG_LOG2E_DIV);
    float lu    = rintf(__builtin_amdgcn_logf(1.0f + e) * LN2_X_65536) * INV_LUT_OUT;
    return fminf(fmaxf(fmaxf(s, v) + lu, QMINF), QMAXF);
}

// Block: 64 spatial lanes x 4 T-quarters = 256 threads. Grid: 2304 blocks.
// __launch_bounds__(256,8): cap VGPRs at 64 so 8 waves/SIMD stay resident.
__global__ __launch_bounds__(256, 8) void QuantizedLogSoftmax_12970801234623_kernel(
    const float* __restrict__ x, float* __restrict__ out) {
    const int lane = threadIdx.x;          // spatial lane [0,64)
    const int yq   = threadIdx.y;          // T-quarter   [0,4)
    const int base = blockIdx.x * 64;      // spatial base of this block
    const int i    = base + lane;

    __shared__ float s_part[NSPLIT][64];
    __shared__ float s_fin[64];

    // ---- Phase 1: each y-wave scans its 64-plane slice (coalesced 256B loads) ----
    const float* xp = x + (size_t)yq * TPER * QLS_HW + i;
    float s = QMINF;
    float vb[PF];
    #pragma unroll
    for (int j = 0; j < PF; ++j) vb[j] = xp[(size_t)j * QLS_HW];
    for (int g = 0; g < TPER / PF - 1; ++g) {
        const float* np = xp + (size_t)(g + 1) * PF * QLS_HW;
        float nb[PF];
        #pragma unroll
        for (int j = 0; j < PF; ++j) nb[j] = np[(size_t)j * QLS_HW];  // next group in flight
        #pragma unroll
        for (int j = 0; j < PF; ++j) s = qls_combine(s, vb[j]);       // consume current
        #pragma unroll
        for (int j = 0; j < PF; ++j) vb[j] = nb[j];
    }
    #pragma unroll
    for (int j = 0; j < PF; ++j) s = qls_combine(s, vb[j]);

    // ---- Merge the 4 partials (left-fold, matches plane order) ----
    s_part[yq][lane] = s;
    __syncthreads();
    if (yq == 0) {
        float t = qls_combine(s_part[0][lane], s_part[1][lane]);
        t = qls_combine(t, s_part[2][lane]);
        t = qls_combine(t, s_part[3][lane]);
        s_fin[lane] = t;
    }
    __syncthreads();

    // ---- Phase 2: float4 quantize+store (1KB/wave-instr; reads are L3 hits) ----
    const int tid = yq * 64 + lane;        // [0,256)
    const int tp  = tid >> 4;              // starting plane [0,16)
    const int j4  = (tid & 15) * 4;        // spatial offset [0,64) step 4
    const float sA = s_fin[j4 + 0];
    const float sB = s_fin[j4 + 1];
    const float sC = s_fin[j4 + 2];
    const float sD = s_fin[j4 + 3];
    const v4f* xv = (const v4f*)x;
    v4f*       ov = (v4f*)out;
    const size_t col = (size_t)(base + j4) >> 2;   // float4-unit column index
    #pragma unroll 4
    for (int t = tp; t < QLS_T; t += 16) {
        size_t idx = (size_t)t * (QLS_HW / 4) + col;
        v4f v = xv[idx];
        v4f q;
        q.x = fminf(fmaxf(rintf((v.x - sA) * Q_SCALE), -128.0f), 127.0f) * INV_Q_SCALE;
        q.y = fminf(fmaxf(rintf((v.y - sB) * Q_SCALE), -128.0f), 127.0f) * INV_Q_SCALE;
        q.z = fminf(fmaxf(rintf((v.z - sC) * Q_SCALE), -128.0f), 127.0f) * INV_Q_SCALE;
        q.w = fminf(fmaxf(rintf((v.w - sD) * Q_SCALE), -128.0f), 127.0f) * INV_Q_SCALE;
        __builtin_nontemporal_store(q, ov + idx);  // out never re-read
    }
}

extern "C" void kernel_launch(void* const* d_in, const int* in_sizes, int n_in,
                              void* d_out, int out_size, void* d_ws, size_t ws_size,
                              hipStream_t stream) {
    const float* x = (const float*)d_in[0];
    float* out = (float*)d_out;
    dim3 block(64, NSPLIT, 1);            // 256 threads
    dim3 grid(QLS_HW / 64, 1, 1);         // 2304 blocks
    QuantizedLogSoftmax_12970801234623_kernel<<<grid, block, 0, stream>>>(x, out);
}